// Round 3
// baseline (1088.084 us; speedup 1.0000x reference)
//
#include <hip/hip_runtime.h>
#include <hip/hip_bf16.h>

#define N_RES   20000
#define N_EDGE  640000
#define NFEAT   340

// freq[m] = exp(2m * (-ln(10000)/16)) = 10^(-m/2)
__device__ __constant__ float c_freq[8] = {
    1.0f, 0.31622776601683794f, 0.1f, 0.031622776601683794f,
    0.01f, 0.0031622776601683794f, 0.001f, 0.00031622776601683794f};

// Per-residue precompute: bb[12] (N,CA,C,virtual CB), local[12] = R^T(bb-t),
// R[9], t[3]  -> 36 floats per residue in workspace.
extern "C" __global__ __launch_bounds__(256)
void residue_prep(const float* __restrict__ atom14,
                  const float* __restrict__ rigids7,
                  float* __restrict__ res) {
    int r = blockIdx.x * 256 + threadIdx.x;
    if (r >= N_RES) return;

    const float* a = atom14 + (size_t)r * 42;  // 14 atoms * 3
    float nx  = a[0], ny  = a[1], nz  = a[2];
    float cax = a[3], cay = a[4], caz = a[5];
    float cx  = a[6], cy  = a[7], cz  = a[8];

    // virtual CB
    float bx = cax - nx, by = cay - ny, bz = caz - nz;     // b  = ca - n
    float ex = cx - cax, ey = cy - cay, ez = cz - caz;     // cc = c - ca
    float ax = by * ez - bz * ey;                          // a = cross(b, cc)
    float ay = bz * ex - bx * ez;
    float az = bx * ey - by * ex;
    float cbx = -0.58273431f * ax + 0.56802827f * bx - 0.54067466f * ex + cax;
    float cby = -0.58273431f * ay + 0.56802827f * by - 0.54067466f * ey + cay;
    float cbz = -0.58273431f * az + 0.56802827f * bz - 0.54067466f * ez + caz;

    const float* q7 = rigids7 + (size_t)r * 7;
    float qw = q7[0], qx = q7[1], qy = q7[2], qz = q7[3];
    float inv = 1.0f / sqrtf(qw * qw + qx * qx + qy * qy + qz * qz);
    qw *= inv; qx *= inv; qy *= inv; qz *= inv;
    float tx = q7[4], ty = q7[5], tz = q7[6];

    // R[j*3+i] : row j, col i (matches _quat_to_rot stacking)
    float R[9];
    R[0] = 1.0f - 2.0f * (qy * qy + qz * qz);
    R[1] = 2.0f * (qx * qy - qw * qz);
    R[2] = 2.0f * (qx * qz + qw * qy);
    R[3] = 2.0f * (qx * qy + qw * qz);
    R[4] = 1.0f - 2.0f * (qx * qx + qz * qz);
    R[5] = 2.0f * (qy * qz - qw * qx);
    R[6] = 2.0f * (qx * qz - qw * qy);
    R[7] = 2.0f * (qy * qz + qw * qx);
    R[8] = 1.0f - 2.0f * (qx * qx + qy * qy);

    float bb[12] = {nx, ny, nz, cax, cay, caz, cx, cy, cz, cbx, cby, cbz};

    float* o = res + (size_t)r * 36;
    #pragma unroll
    for (int k = 0; k < 12; ++k) o[k] = bb[k];
    // local[k][i] = sum_j R[j][i] * (bb[k][j] - t[j])   (R^T * x)
    #pragma unroll
    for (int k = 0; k < 4; ++k) {
        float x0 = bb[k * 3 + 0] - tx;
        float x1 = bb[k * 3 + 1] - ty;
        float x2 = bb[k * 3 + 2] - tz;
        #pragma unroll
        for (int i = 0; i < 3; ++i)
            o[12 + k * 3 + i] = R[i] * x0 + R[3 + i] * x1 + R[6 + i] * x2;
    }
    #pragma unroll
    for (int j = 0; j < 9; ++j) o[24 + j] = R[j];
    o[33] = tx; o[34] = ty; o[35] = tz;
}

// One wave (64 lanes) per edge. 4 waves / 256-thread block.
extern "C" __global__ __launch_bounds__(256)
void edge_feats(const int* __restrict__ eidx,
                const int* __restrict__ seq,
                const int* __restrict__ mask,
                const float* __restrict__ res,
                float* __restrict__ out) {
    int lane = threadIdx.x & 63;
    int wave = threadIdx.x >> 6;
    int e = blockIdx.x * 4 + wave;   // grid sized exactly N_EDGE/4

    int dst = eidx[e];
    int src = eidx[N_EDGE + e];
    int msrc = mask[src];
    int mdst = mask[dst];
    float noised_src = msrc ? 1.0f : 0.0f;
    float noised_dst = mdst ? 1.0f : 0.0f;
    float keep_src = 1.0f - noised_src;
    float keep_dst = 1.0f - noised_dst;
    int ssrc = seq[src];
    int sdst = seq[dst];

    const float* rs = res + (size_t)src * 36;
    const float* rd = res + (size_t)dst * 36;

    // Each lane computes distance for pair p = lane & 15 : i = p>>2 (src atom),
    // j = p&3 (dst atom).  D = ||bb_src[i] - bb_dst[j] + EPS||
    int p  = lane & 15;
    int di = p >> 2;
    int dj = p & 3;
    float dx = rs[di * 3 + 0] - rd[dj * 3 + 0] + 1e-8f;
    float dy = rs[di * 3 + 1] - rd[dj * 3 + 1] + 1e-8f;
    float dz = rs[di * 3 + 2] - rd[dj * 3 + 2] + 1e-8f;
    float D = sqrtf(dx * dx + dy * dy + dz * dz);

    float dpos = (float)(dst - src);
    size_t base = (size_t)e * NFEAT;

    #pragma unroll
    for (int it = 0; it < 6; ++it) {
        int f = lane + it * 64;
        bool act = f < NFEAT;
        // Hoist the shuffle out of divergent control flow (uniform exec).
        int q = f - 44;
        int srcLane = (q < 0) ? 0 : ((q >> 4) & 15);
        float Dq = __shfl(D, srcLane, 64);

        float v = 0.0f;
        if (act) {
            if (f < 2) {
                v = (f == 0) ? noised_dst : noised_src;
            } else if (f < 23) {
                v = (ssrc == f - 2) ? keep_src : 0.0f;
            } else if (f < 44) {
                v = (sdst == f - 23) ? keep_dst : 0.0f;
            } else if (f < 300) {
                int r = q & 15;
                float mu = 2.0f + (20.0f / 15.0f) * (float)r;
                float x = (Dq - mu) * 0.8f;   // sigma = 1.25
                v = __expf(-x * x);
            } else if (f < 316) {
                int m = f - 300;
                float ang = dpos * c_freq[m & 7];
                v = (m < 8) ? cosf(ang) : sinf(ang);
            } else if (f < 328) {
                v = rs[12 + (f - 316)] * keep_src;
            } else {
                int qq = f - 328;
                int k = qq / 3;
                int i = qq - k * 3;
                float x0 = rd[k * 3 + 0] - rs[33];
                float x1 = rd[k * 3 + 1] - rs[34];
                float x2 = rd[k * 3 + 2] - rs[35];
                v = (rs[24 + i] * x0 + rs[27 + i] * x1 + rs[30 + i] * x2) * keep_dst;
            }
            out[base + f] = v;
        }
    }
}

extern "C" void kernel_launch(void* const* d_in, const int* in_sizes, int n_in,
                              void* d_out, int out_size, void* d_ws, size_t ws_size,
                              hipStream_t stream) {
    const float* atom14  = (const float*)d_in[0];
    const float* rigids7 = (const float*)d_in[1];
    const int* seq  = (const int*)d_in[2];
    const int* mask = (const int*)d_in[3];
    const int* eidx = (const int*)d_in[4];
    float* res = (float*)d_ws;   // 20000 * 36 floats = 2.88 MB

    hipLaunchKernelGGL(residue_prep, dim3((N_RES + 255) / 256), dim3(256), 0, stream,
                       atom14, rigids7, res);
    hipLaunchKernelGGL(edge_feats, dim3(N_EDGE / 4), dim3(256), 0, stream,
                       eidx, seq, mask, res, (float*)d_out);
}